// Round 8
// baseline (7772.517 us; speedup 1.0000x reference)
//
#include <hip/hip_runtime.h>
#include <math.h>

#define B_ 1024
#define T_ 128
#define H_ 2048
#define C_ 10

typedef __bf16 bf16_t;
typedef __bf16 bf16x8 __attribute__((ext_vector_type(8)));
typedef __bf16 bf16x4 __attribute__((ext_vector_type(4)));
typedef float f32x4 __attribute__((ext_vector_type(4)));

// Static device storage: bf16 h ping-pong (8 MB), bf16 W_hh^T (8 MB),
// per-(t,bm) readiness counters for the cross-step handoff.
__device__ __align__(16) bf16_t g_hb[2][(size_t)B_ * H_];
__device__ __align__(16) bf16_t g_whhT[(size_t)H_ * H_];
__device__ int g_cnt[T_ * 8];   // [t][bm]; t=0 seeded to 32 by rnn_init

__device__ __forceinline__ void gload16(const bf16_t* g, bf16_t* l) {
    __builtin_amdgcn_global_load_lds(
        (const __attribute__((address_space(1))) void*)g,
        (__attribute__((address_space(3))) void*)l, 16, 0, 0);
}

// Counted-vmcnt barrier: retire oldest pipeline stage without draining.
template <int VM>
__device__ __forceinline__ void wait_vm_barrier() {
    asm volatile("s_waitcnt vmcnt(%0)\n\ts_barrier" :: "n"(VM) : "memory");
}

// One-time: W_hhT[n][k] = bf16(W_hh[k][n]) — B operand must be K-contiguous.
__global__ __launch_bounds__(256) void prep_whhT(const float* __restrict__ Whh) {
    __shared__ float tile[32][33];
    const int i  = threadIdx.x >> 3;
    const int j4 = (threadIdx.x & 7) * 4;
    const int r0 = blockIdx.y * 32;
    const int c0 = blockIdx.x * 32;
    f32x4 v = *(const f32x4*)(Whh + (size_t)(r0 + i) * H_ + c0 + j4);
    tile[i][j4 + 0] = v[0]; tile[i][j4 + 1] = v[1];
    tile[i][j4 + 2] = v[2]; tile[i][j4 + 3] = v[3];
    __syncthreads();
    bf16x4 o;
#pragma unroll
    for (int r = 0; r < 4; ++r) o[r] = (bf16_t)tile[j4 + r][i];
    *(bf16x4*)&g_whhT[(size_t)(c0 + i) * H_ + r0 + j4] = o;
}

// t = 0: h = tanh(x[:,0]*W_hx + b_h); also (re)initialize the counters.
__global__ __launch_bounds__(256) void rnn_init(const float* __restrict__ x,
                                                const float* __restrict__ Whx,
                                                const float* __restrict__ bh) {
    if (blockIdx.x == 0) {
        for (int i = threadIdx.x; i < T_ * 8; i += 256)
            g_cnt[i] = (i < 8) ? 32 : 0;   // g_cnt[0][*] = 32 (h0 ready)
    }
    const int gid = blockIdx.x * 256 + threadIdx.x;
    const int row = gid >> 9;
    const int col = (gid & 511) << 2;
    const float xv = x[(size_t)row * T_];
    f32x4 w = *(const f32x4*)&Whx[col];
    f32x4 b = *(const f32x4*)&bh[col];
    bf16x4 o;
#pragma unroll
    for (int j = 0; j < 4; ++j) o[j] = (bf16_t)tanhf(fmaf(xv, w[j], b[j]));
    *(bf16x4*)&g_hb[0][(size_t)row * H_ + col] = o;
}

// Persistent RNN: all 127 steps in one launch. Grid 256 = 1 block/CU (96 KB
// LDS forces 1/CU -> all blocks co-resident; spin-wait is safe).
// Per step: 128(M)x64(N) tile, BK=64 (32 iters), 4 waves x 64x32, 4-stage
// LDS ring, counted-vmcnt barriers. Cross-step dependency is per-bm only
// (batch rows are independent chains): writers release-add g_cnt[t][bm],
// readers of the same bm spin on g_cnt[t-1][bm]==32. B (W_hh^T) is static,
// so its first 3 stages are prefetched BEFORE the spin/acquire.
__global__ __launch_bounds__(256, 1) void rnn_persist(const float* __restrict__ x,
                                                      const float* __restrict__ Whx,
                                                      const float* __restrict__ bh) {
    extern __shared__ __align__(16) bf16_t smem[];
    bf16_t* As = smem;                 // 4 stages x 8192 elems (16 KB)
    bf16_t* Bs = smem + 4 * 8192;      // 4 stages x 4096 elems (8 KB)

    const int tid  = threadIdx.x;
    const int lane = tid & 63;
    const int wave = tid >> 6;
    // XCD-region swizzle (r7): xcd owns 4bm x 8bn -> A 2MB + B 2MB in L2.
    const int li  = blockIdx.x;
    const int xcd = li & 7;
    const int p   = li >> 3;                         // 0..31
    const int bm  = (xcd & 1) * 4 + (p & 3);         // 0..7
    const int bn  = (xcd >> 1) * 8 + (p >> 2);       // 0..31

    const int wm = (wave & 1) * 64, wn = (wave >> 1) * 32;
    const int fr = lane & 15, fq = lane >> 4;

    // Staging: linear slot s holds row s>>3, lds-chunk s&7;
    // global chunk = (s&7) ^ (row&7)  (8-row spread -> 2-way frag reads).
    const int rA = tid >> 3;                         // 0..31
    const int cg = (tid & 7) ^ (rA & 7);
    const size_t aofsg = (size_t)(bm * 128 + rA) * H_ + cg * 8;
    const bf16_t* const gb0 = g_whhT + (size_t)(bn * 64 + rA) * H_ + cg * 8;

#define ISSUE_A(SLOT)                                                    \
    do {                                                                 \
        gload16(gpa,            As + (SLOT) * 8192 + tid * 8);           \
        gload16(gpa + 32 * H_,  As + (SLOT) * 8192 + (tid + 256) * 8);   \
        gload16(gpa + 64 * H_,  As + (SLOT) * 8192 + (tid + 512) * 8);   \
        gload16(gpa + 96 * H_,  As + (SLOT) * 8192 + (tid + 768) * 8);   \
        gpa += 64;                                                       \
    } while (0)
#define ISSUE_B(SLOT)                                                    \
    do {                                                                 \
        gload16(gpb,            Bs + (SLOT) * 4096 + tid * 8);           \
        gload16(gpb + 32 * H_,  Bs + (SLOT) * 4096 + (tid + 256) * 8);   \
        gpb += 64;                                                       \
    } while (0)
#define ISSUE_AB(SLOT) do { ISSUE_A(SLOT); ISSUE_B(SLOT); } while (0)

    // frag offsets (elems): row*64 + ((cc*4+fq) ^ (row&7))*8; row&7 == fr&7.
    const int xr0 = (fq ^ (fr & 7)) * 8;
    const int xr1 = ((4 + fq) ^ (fr & 7)) * 8;
    int aoff[4][2], boff[2][2];
#pragma unroll
    for (int i = 0; i < 4; ++i) {
        aoff[i][0] = (wm + i * 16 + fr) * 64 + xr0;
        aoff[i][1] = (wm + i * 16 + fr) * 64 + xr1;
    }
#pragma unroll
    for (int j = 0; j < 2; ++j) {
        boff[j][0] = (wn + j * 16 + fr) * 64 + xr0;
        boff[j][1] = (wn + j * 16 + fr) * 64 + xr1;
    }

#define COMPUTE(SLOT)                                                       \
    {                                                                       \
        _Pragma("unroll")                                                   \
        for (int cc = 0; cc < 2; ++cc) {                                    \
            bf16x8 af[4], bfv[2];                                           \
            _Pragma("unroll")                                               \
            for (int j = 0; j < 2; ++j)                                     \
                bfv[j] = *(const bf16x8*)(Bs + (SLOT) * 4096 + boff[j][cc]);\
            _Pragma("unroll")                                               \
            for (int i = 0; i < 4; ++i)                                     \
                af[i] = *(const bf16x8*)(As + (SLOT) * 8192 + aoff[i][cc]); \
            _Pragma("unroll")                                               \
            for (int i = 0; i < 4; ++i)                                     \
                _Pragma("unroll")                                           \
                for (int j = 0; j < 2; ++j)                                 \
                    acc[i][j] = __builtin_amdgcn_mfma_f32_16x16x32_bf16(    \
                        af[i], bfv[j], acc[i][j], 0, 0, 0);                 \
        }                                                                   \
    }

    // epilogue constants (step-invariant)
    float wv[2], bv[2];
    int xbase[4];
#pragma unroll
    for (int j = 0; j < 2; ++j) {
        const int col = bn * 64 + wn + j * 16 + fr;
        wv[j] = Whx[col];
        bv[j] = bh[col];
    }
#pragma unroll
    for (int i = 0; i < 4; ++i)
        xbase[i] = (bm * 128 + wm + i * 16 + fq * 4) * T_;

    for (int t = 1; t < T_; ++t) {
        const bf16_t* __restrict__ Abuf = g_hb[(t - 1) & 1];
        bf16_t* __restrict__ hn = g_hb[t & 1];
        const bf16_t* gpa = Abuf + aofsg;
        const bf16_t* gpb = gb0;

        // B stages 0..2: static data, issue before the dependency wait.
        ISSUE_B(0); ISSUE_B(1); ISSUE_B(2);

        // wait until all 32 writers of A-rows bm finished step t-1
        if (tid == 0) {
            while (__hip_atomic_load(&g_cnt[(t - 1) * 8 + bm], __ATOMIC_RELAXED,
                                     __HIP_MEMORY_SCOPE_AGENT) != 32)
                __builtin_amdgcn_s_sleep(2);
        }
        __syncthreads();
        __builtin_amdgcn_fence(__ATOMIC_ACQUIRE, "agent");

        ISSUE_A(0); ISSUE_A(1); ISSUE_A(2);

        f32x4 acc[4][2];
#pragma unroll
        for (int i = 0; i < 4; ++i)
#pragma unroll
            for (int j = 0; j < 2; ++j) acc[i][j] = (f32x4)(0.f);

        // Queue order this step: B0 B1 B2 | A0 A1 A2 | S3 S4 ... (6/stage).
        // it0 needs B0+A0 -> vmcnt 8; it1 needs A1 -> 10; it2 -> 12; then 12.
        wait_vm_barrier<8>();  ISSUE_AB(3); COMPUTE(0);
        wait_vm_barrier<10>(); ISSUE_AB(0); COMPUTE(1);
        wait_vm_barrier<12>(); ISSUE_AB(1); COMPUTE(2);
        for (int g = 0; g < 6; ++g) {
#pragma unroll
            for (int u = 0; u < 4; ++u) {     // iters 3..26
                wait_vm_barrier<12>();
                ISSUE_AB((u + 2) & 3);
                COMPUTE((u + 3) & 3);
            }
        }
        wait_vm_barrier<12>(); ISSUE_AB(2); COMPUTE(3);   // it27 (stage 30)
        wait_vm_barrier<12>(); ISSUE_AB(3); COMPUTE(0);   // it28 (stage 31)
        wait_vm_barrier<12>(); COMPUTE(1);                // drain
        wait_vm_barrier<6>();  COMPUTE(2);
        wait_vm_barrier<0>();  COMPUTE(3);

        // epilogue: + x_t*W_hx + b_h, tanh, bf16 store
#pragma unroll
        for (int i = 0; i < 4; ++i) {
            const int row0 = bm * 128 + wm + i * 16 + fq * 4;
            float xv[4];
#pragma unroll
            for (int r = 0; r < 4; ++r) xv[r] = x[xbase[i] + r * T_ + t];
#pragma unroll
            for (int j = 0; j < 2; ++j) {
                const int col = bn * 64 + wn + j * 16 + fr;
#pragma unroll
                for (int r = 0; r < 4; ++r)
                    hn[(size_t)(row0 + r) * H_ + col] =
                        (bf16_t)tanhf(acc[i][j][r] + xv[r] * wv[j] + bv[j]);
            }
        }

        __threadfence();
        __syncthreads();
        if (tid == 0)
            __hip_atomic_fetch_add(&g_cnt[t * 8 + bm], 1, __ATOMIC_RELEASE,
                                   __HIP_MEMORY_SCOPE_AGENT);
    }
#undef COMPUTE
#undef ISSUE_AB
#undef ISSUE_B
#undef ISSUE_A
}

// p = h_T @ W_ph + b_p : one wave per batch row, fp32 accumulate.
__global__ __launch_bounds__(64) void rnn_proj(const float* __restrict__ Wph,
                                               const float* __restrict__ bp,
                                               float* __restrict__ out, int sb) {
    const int b = blockIdx.x;
    const int l = threadIdx.x;
    const bf16_t* h = g_hb[sb] + (size_t)b * H_;
    float acc[C_];
#pragma unroll
    for (int c = 0; c < C_; ++c) acc[c] = 0.f;
    for (int k = l; k < H_; k += 64) {
        const float hv = (float)h[k];
#pragma unroll
        for (int c = 0; c < C_; ++c)
            acc[c] = fmaf(hv, Wph[k * C_ + c], acc[c]);
    }
#pragma unroll
    for (int off = 32; off > 0; off >>= 1)
#pragma unroll
        for (int c = 0; c < C_; ++c) acc[c] += __shfl_down(acc[c], off);
    if (l == 0) {
#pragma unroll
        for (int c = 0; c < C_; ++c) out[b * C_ + c] = acc[c] + bp[c];
    }
}

extern "C" void kernel_launch(void* const* d_in, const int* in_sizes, int n_in,
                              void* d_out, int out_size, void* d_ws, size_t ws_size,
                              hipStream_t stream) {
    const float* x   = (const float*)d_in[0];   // [1024,128]
    const float* Whx = (const float*)d_in[1];   // [1,2048]
    const float* Whh = (const float*)d_in[2];   // [2048,2048]
    const float* bh  = (const float*)d_in[3];   // [2048]
    const float* Wph = (const float*)d_in[4];   // [2048,10]
    const float* bp  = (const float*)d_in[5];   // [1,10]
    float* out = (float*)d_out;                 // [1024,10]

    static bool attr_set = false;
    if (!attr_set) {
        hipFuncSetAttribute((const void*)rnn_persist,
                            hipFuncAttributeMaxDynamicSharedMemorySize, 98304);
        attr_set = true;
    }

    prep_whhT<<<dim3(64, 64), 256, 0, stream>>>(Whh);
    rnn_init<<<(B_ * H_ / 4) / 256, 256, 0, stream>>>(x, Whx, bh);
    rnn_persist<<<256, 256, 98304, stream>>>(x, Whx, bh);
    rnn_proj<<<B_, 64, 0, stream>>>(Wph, bp, out, (T_ - 1) & 1);
}

// Round 9
// 2920.324 us; speedup vs baseline: 2.6615x; 2.6615x over previous
//
#include <hip/hip_runtime.h>
#include <math.h>

#define B_ 1024
#define T_ 128
#define H_ 2048
#define C_ 10

typedef __bf16 bf16_t;
typedef __bf16 bf16x8 __attribute__((ext_vector_type(8)));
typedef __bf16 bf16x4 __attribute__((ext_vector_type(4)));
typedef float f32x4 __attribute__((ext_vector_type(4)));

// Static device storage: bf16 h ping-pong (8 MB), bf16 W_hh^T (8 MB).
__device__ __align__(16) bf16_t g_hb[2][(size_t)B_ * H_];
__device__ __align__(16) bf16_t g_whhT[(size_t)H_ * H_];

__device__ __forceinline__ void gload16(const bf16_t* g, bf16_t* l) {
    __builtin_amdgcn_global_load_lds(
        (const __attribute__((address_space(1))) void*)g,
        (__attribute__((address_space(3))) void*)l, 16, 0, 0);
}

// Counted-vmcnt barrier: retire oldest pipeline stage without draining.
template <int VM>
__device__ __forceinline__ void wait_vm_barrier() {
    asm volatile("s_waitcnt vmcnt(%0)\n\ts_barrier" :: "n"(VM) : "memory");
}

// One-time: W_hhT[n][k] = bf16(W_hh[k][n]) — B operand must be K-contiguous.
__global__ __launch_bounds__(256) void prep_whhT(const float* __restrict__ Whh) {
    __shared__ float tile[32][33];
    const int i  = threadIdx.x >> 3;
    const int j4 = (threadIdx.x & 7) * 4;
    const int r0 = blockIdx.y * 32;
    const int c0 = blockIdx.x * 32;
    f32x4 v = *(const f32x4*)(Whh + (size_t)(r0 + i) * H_ + c0 + j4);
    tile[i][j4 + 0] = v[0]; tile[i][j4 + 1] = v[1];
    tile[i][j4 + 2] = v[2]; tile[i][j4 + 3] = v[3];
    __syncthreads();
    bf16x4 o;
#pragma unroll
    for (int r = 0; r < 4; ++r) o[r] = (bf16_t)tile[j4 + r][i];
    *(bf16x4*)&g_whhT[(size_t)(c0 + i) * H_ + r0 + j4] = o;
}

// t = 0: h = tanh(x[:,0]*W_hx + b_h)  (h0 == 0) -> bf16
__global__ __launch_bounds__(256) void rnn_init(const float* __restrict__ x,
                                                const float* __restrict__ Whx,
                                                const float* __restrict__ bh) {
    const int gid = blockIdx.x * 256 + threadIdx.x;
    const int row = gid >> 9;
    const int col = (gid & 511) << 2;
    const float xv = x[(size_t)row * T_];
    f32x4 w = *(const f32x4*)&Whx[col];
    f32x4 b = *(const f32x4*)&bh[col];
    bf16x4 o;
#pragma unroll
    for (int j = 0; j < 4; ++j) o[j] = (bf16_t)tanhf(fmaf(xv, w[j], b[j]));
    *(bf16x4*)&g_hb[0][(size_t)row * H_ + col] = o;
}

// Fused RNN step: h[db] = tanh(h[sb] @ W_hh + x[:,t]*W_hx + b_h), bf16 out.
// 128(M)x64(N) block tile, 2 waves x (64x64) wave tile (max AI: each LDS
// byte feeds 64 MFLOP-col/rows; no wave-pair read duplication), BK=64
// (32 iters), grid 256 = 1 block/CU. 4-stage LDS ring (96 KB), 3 stages in
// flight, counted-vmcnt barriers. XOR k-chunk swizzle keeps frag
// ds_read_b128 at 2-way (free) with the lane-linear global_load_lds layout.
// XCD map (heuristic, perf-only): xcd owns 4bm x 8bn -> A 2MB + B 2MB in L2.
__global__ __launch_bounds__(128, 1) void rnn_step(const float* __restrict__ x,
                                                   const float* __restrict__ Whx,
                                                   const float* __restrict__ bh,
                                                   int t, int sb, int db) {
    extern __shared__ __align__(16) bf16_t smem[];
    bf16_t* As = smem;                 // 4 stages x 8192 elems (16 KB)
    bf16_t* Bs = smem + 4 * 8192;      // 4 stages x 4096 elems (8 KB)

    const int tid  = threadIdx.x;      // 0..127
    const int lane = tid & 63;
    const int wave = tid >> 6;         // 0..1
    // XCD-region swizzle (r7): xcd = li&7 owns a 4bm x 8bn region.
    const int li  = blockIdx.x;
    const int xcd = li & 7;
    const int p   = li >> 3;                         // 0..31
    const int bm  = (xcd & 1) * 4 + (p & 3);         // 0..7
    const int bn  = (xcd >> 1) * 8 + (p >> 2);       // 0..31

    const int wm = wave * 64;          // wave's M offset; N = full 64
    const int fr = lane & 15, fq = lane >> 4;

    // Staging (per stage: A 128x64, B 64x64): thread t covers rows
    // srow + 16*l; k-chunk swizzled by row so frag reads are 2-way max.
    const int srow = tid >> 3;                       // 0..15
    const int cg   = (tid & 7) ^ (srow & 7);         // global chunk in slot tid&7
    const bf16_t* gpa = g_hb[sb] + (size_t)(bm * 128 + srow) * H_ + cg * 8;
    const bf16_t* gpb = g_whhT  + (size_t)(bn * 64  + srow) * H_ + cg * 8;
    const int dstA = wave * 512 + lane * 8;          // + l*1024 per row-group
    const int dstB = wave * 512 + lane * 8;

#define ISSUE(SLOT)                                                         \
    do {                                                                    \
        _Pragma("unroll")                                                   \
        for (int l = 0; l < 8; ++l)                                         \
            gload16(gpa + (size_t)l * 16 * H_,                              \
                    As + (SLOT) * 8192 + dstA + l * 1024);                  \
        _Pragma("unroll")                                                   \
        for (int q = 0; q < 4; ++q)                                         \
            gload16(gpb + (size_t)q * 16 * H_,                              \
                    Bs + (SLOT) * 4096 + dstB + q * 1024);                  \
        gpa += 64; gpb += 64;                                               \
    } while (0)

    // prologue: stages 0,1,2 (36 loads/thread in flight)
    ISSUE(0); ISSUE(1); ISSUE(2);

    f32x4 acc[4][4];
#pragma unroll
    for (int i = 0; i < 4; ++i)
#pragma unroll
        for (int j = 0; j < 4; ++j) acc[i][j] = (f32x4)(0.f);

    // frag offsets (elems): row*64 + ((cc*4+fq) ^ (row&7))*8; row&7 == fr&7.
    const int xr0 = (fq ^ (fr & 7)) * 8;
    const int xr1 = ((4 + fq) ^ (fr & 7)) * 8;
    int aoff[4][2], boff[4][2];
#pragma unroll
    for (int i = 0; i < 4; ++i) {
        aoff[i][0] = (wm + i * 16 + fr) * 64 + xr0;
        aoff[i][1] = (wm + i * 16 + fr) * 64 + xr1;
        boff[i][0] = (i * 16 + fr) * 64 + xr0;
        boff[i][1] = (i * 16 + fr) * 64 + xr1;
    }

#define COMPUTE(SLOT)                                                       \
    {                                                                       \
        _Pragma("unroll")                                                   \
        for (int cc = 0; cc < 2; ++cc) {                                    \
            bf16x8 af[4], bfv[4];                                           \
            _Pragma("unroll")                                               \
            for (int j = 0; j < 4; ++j)                                     \
                bfv[j] = *(const bf16x8*)(Bs + (SLOT) * 4096 + boff[j][cc]);\
            _Pragma("unroll")                                               \
            for (int i = 0; i < 4; ++i)                                     \
                af[i] = *(const bf16x8*)(As + (SLOT) * 8192 + aoff[i][cc]); \
            _Pragma("unroll")                                               \
            for (int i = 0; i < 4; ++i)                                     \
                _Pragma("unroll")                                           \
                for (int j = 0; j < 4; ++j)                                 \
                    acc[i][j] = __builtin_amdgcn_mfma_f32_16x16x32_bf16(    \
                        af[i], bfv[j], acc[i][j], 0, 0, 0);                 \
        }                                                                   \
    }

    // it 0
    wait_vm_barrier<24>(); ISSUE(3); COMPUTE(0);
    // its 1..28 (issue stages 4..31)
    for (int g = 0; g < 7; ++g) {
#pragma unroll
        for (int u = 0; u < 4; ++u) {
            wait_vm_barrier<24>();
            ISSUE(u);
            COMPUTE((u + 1) & 3);
        }
    }
    // drain: its 29,30,31
    wait_vm_barrier<24>(); COMPUTE(1);
    wait_vm_barrier<12>(); COMPUTE(2);
    wait_vm_barrier<0>();  COMPUTE(3);
#undef COMPUTE
#undef ISSUE

    // epilogue: + x_t*W_hx + b_h, tanh, bf16 store
    bf16_t* __restrict__ hn = g_hb[db];
    float wv[4], bv[4];
#pragma unroll
    for (int j = 0; j < 4; ++j) {
        const int col = bn * 64 + j * 16 + fr;
        wv[j] = Whx[col];
        bv[j] = bh[col];
    }
#pragma unroll
    for (int i = 0; i < 4; ++i) {
        const int row0 = bm * 128 + wm + i * 16 + fq * 4;
        float xv[4];
#pragma unroll
        for (int r = 0; r < 4; ++r) xv[r] = x[(size_t)(row0 + r) * T_ + t];
#pragma unroll
        for (int j = 0; j < 4; ++j) {
            const int col = bn * 64 + j * 16 + fr;
#pragma unroll
            for (int r = 0; r < 4; ++r)
                hn[(size_t)(row0 + r) * H_ + col] =
                    (bf16_t)tanhf(acc[i][j][r] + xv[r] * wv[j] + bv[j]);
        }
    }
}

// p = h_T @ W_ph + b_p : one wave per batch row, fp32 accumulate.
__global__ __launch_bounds__(64) void rnn_proj(const float* __restrict__ Wph,
                                               const float* __restrict__ bp,
                                               float* __restrict__ out, int sb) {
    const int b = blockIdx.x;
    const int l = threadIdx.x;
    const bf16_t* h = g_hb[sb] + (size_t)b * H_;
    float acc[C_];
#pragma unroll
    for (int c = 0; c < C_; ++c) acc[c] = 0.f;
    for (int k = l; k < H_; k += 64) {
        const float hv = (float)h[k];
#pragma unroll
        for (int c = 0; c < C_; ++c)
            acc[c] = fmaf(hv, Wph[k * C_ + c], acc[c]);
    }
#pragma unroll
    for (int off = 32; off > 0; off >>= 1)
#pragma unroll
        for (int c = 0; c < C_; ++c) acc[c] += __shfl_down(acc[c], off);
    if (l == 0) {
#pragma unroll
        for (int c = 0; c < C_; ++c) out[b * C_ + c] = acc[c] + bp[c];
    }
}

extern "C" void kernel_launch(void* const* d_in, const int* in_sizes, int n_in,
                              void* d_out, int out_size, void* d_ws, size_t ws_size,
                              hipStream_t stream) {
    const float* x   = (const float*)d_in[0];   // [1024,128]
    const float* Whx = (const float*)d_in[1];   // [1,2048]
    const float* Whh = (const float*)d_in[2];   // [2048,2048]
    const float* bh  = (const float*)d_in[3];   // [2048]
    const float* Wph = (const float*)d_in[4];   // [2048,10]
    const float* bp  = (const float*)d_in[5];   // [1,10]
    float* out = (float*)d_out;                 // [1024,10]

    static bool attr_set = false;
    if (!attr_set) {
        hipFuncSetAttribute((const void*)rnn_step,
                            hipFuncAttributeMaxDynamicSharedMemorySize, 98304);
        attr_set = true;
    }

    prep_whhT<<<dim3(64, 64), 256, 0, stream>>>(Whh);
    rnn_init<<<(B_ * H_ / 4) / 256, 256, 0, stream>>>(x, Whx, bh);

    int src = 0;
    for (int t = 1; t < T_; ++t) {
        rnn_step<<<256, 128, 98304, stream>>>(x, Whx, bh, t, src, 1 - src);
        src = 1 - src;
    }
    rnn_proj<<<B_, 64, 0, stream>>>(Wph, bp, out, src);
}

// Round 10
// 2579.025 us; speedup vs baseline: 3.0137x; 1.1323x over previous
//
#include <hip/hip_runtime.h>
#include <math.h>

#define B_ 1024
#define T_ 128
#define H_ 2048
#define C_ 10

typedef __bf16 bf16_t;
typedef __bf16 bf16x8 __attribute__((ext_vector_type(8)));
typedef __bf16 bf16x4 __attribute__((ext_vector_type(4)));
typedef float f32x4 __attribute__((ext_vector_type(4)));

// Static device storage: bf16 h ping-pong (8 MB), bf16 W_hh^T (8 MB),
// per-(t,bm) readiness counters (XCD-local handoff).
__device__ __align__(16) bf16_t g_hb[2][(size_t)B_ * H_];
__device__ __align__(16) bf16_t g_whhT[(size_t)H_ * H_];
__device__ int g_cnt[T_ * 8];   // [t][bm]; t=0 seeded to 32 by rnn_init

// AUX: cache policy. 0 = default; 1 = sc0 (force L1 miss -> read XCD L2).
template <int AUX>
__device__ __forceinline__ void gload16(const bf16_t* g, bf16_t* l) {
    __builtin_amdgcn_global_load_lds(
        (const __attribute__((address_space(1))) void*)g,
        (__attribute__((address_space(3))) void*)l, 16, 0, AUX);
}

// Counted-vmcnt barrier: retire oldest pipeline stage without draining.
template <int VM>
__device__ __forceinline__ void wait_vm_barrier() {
    asm volatile("s_waitcnt vmcnt(%0)\n\ts_barrier" :: "n"(VM) : "memory");
}

// One-time: W_hhT[n][k] = bf16(W_hh[k][n]) — B operand must be K-contiguous.
__global__ __launch_bounds__(256) void prep_whhT(const float* __restrict__ Whh) {
    __shared__ float tile[32][33];
    const int i  = threadIdx.x >> 3;
    const int j4 = (threadIdx.x & 7) * 4;
    const int r0 = blockIdx.y * 32;
    const int c0 = blockIdx.x * 32;
    f32x4 v = *(const f32x4*)(Whh + (size_t)(r0 + i) * H_ + c0 + j4);
    tile[i][j4 + 0] = v[0]; tile[i][j4 + 1] = v[1];
    tile[i][j4 + 2] = v[2]; tile[i][j4 + 3] = v[3];
    __syncthreads();
    bf16x4 o;
#pragma unroll
    for (int r = 0; r < 4; ++r) o[r] = (bf16_t)tile[j4 + r][i];
    *(bf16x4*)&g_whhT[(size_t)(c0 + i) * H_ + r0 + j4] = o;
}

// t = 0: h = tanh(x[:,0]*W_hx + b_h); also (re)initialize the counters.
__global__ __launch_bounds__(256) void rnn_init(const float* __restrict__ x,
                                                const float* __restrict__ Whx,
                                                const float* __restrict__ bh) {
    if (blockIdx.x == 0) {
        for (int i = threadIdx.x; i < T_ * 8; i += 256)
            g_cnt[i] = (i < 8) ? 32 : 0;   // g_cnt[0][*] = 32 (h0 ready)
    }
    const int gid = blockIdx.x * 256 + threadIdx.x;
    const int row = gid >> 9;
    const int col = (gid & 511) << 2;
    const float xv = x[(size_t)row * T_];
    f32x4 w = *(const f32x4*)&Whx[col];
    f32x4 b = *(const f32x4*)&bh[col];
    bf16x4 o;
#pragma unroll
    for (int j = 0; j < 4; ++j) o[j] = (bf16_t)tanhf(fmaf(xv, w[j], b[j]));
    *(bf16x4*)&g_hb[0][(size_t)row * H_ + col] = o;
}

// Persistent RNN, XCD-local sync. Grid 256 = 1 block/CU (96 KB LDS forces
// co-residency). Map bm = li&7 = XCD: the 32 writers of h-rows [bm*128,+128)
// are exactly XCD bm's 32 blocks, so cross-step coherence lives entirely in
// that XCD's L2. NO agent fences (r8's 3x regression was their L2
// writeback+invalidate): writers drain stores (vmcnt(0), write-through L1
// -> L2), publish with a relaxed agent-scope atomic (L2-executed); readers
// poll the atomic and stage A with sc0 (aux=1) loads that bypass stale L1.
// B (W_hh^T, immutable) stages with default policy, issued before the spin.
// Per step: 128x64 tile, BK=64 (32 iters), 4 waves x 64x32, 4-stage ring.
__global__ __launch_bounds__(256, 1) void rnn_persist(const float* __restrict__ x,
                                                      const float* __restrict__ Whx,
                                                      const float* __restrict__ bh) {
    extern __shared__ __align__(16) bf16_t smem[];
    bf16_t* As = smem;                 // 4 stages x 8192 elems (16 KB)
    bf16_t* Bs = smem + 4 * 8192;      // 4 stages x 4096 elems (8 KB)

    const int tid  = threadIdx.x;
    const int lane = tid & 63;
    const int wave = tid >> 6;
    const int li  = blockIdx.x;
    const int bm  = li & 7;                          // == XCD (blk%8 map)
    const int bn  = li >> 3;                         // 0..31

    const int wm = (wave & 1) * 64, wn = (wave >> 1) * 32;
    const int fr = lane & 15, fq = lane >> 4;

    // Staging: linear slot s holds row s>>3, lds-chunk s&7;
    // global chunk = (s&7) ^ (row&7)  (8-row spread -> 2-way frag reads).
    const int rA = tid >> 3;                         // 0..31
    const int cg = (tid & 7) ^ (rA & 7);
    const size_t aofsg = (size_t)(bm * 128 + rA) * H_ + cg * 8;
    const bf16_t* const gb0 = g_whhT + (size_t)(bn * 64 + rA) * H_ + cg * 8;

#define ISSUE_A(SLOT)                                                    \
    do {                                                                 \
        gload16<1>(gpa,            As + (SLOT) * 8192 + tid * 8);        \
        gload16<1>(gpa + 32 * H_,  As + (SLOT) * 8192 + (tid + 256) * 8);\
        gload16<1>(gpa + 64 * H_,  As + (SLOT) * 8192 + (tid + 512) * 8);\
        gload16<1>(gpa + 96 * H_,  As + (SLOT) * 8192 + (tid + 768) * 8);\
        gpa += 64;                                                       \
    } while (0)
#define ISSUE_B(SLOT)                                                    \
    do {                                                                 \
        gload16<0>(gpb,            Bs + (SLOT) * 4096 + tid * 8);        \
        gload16<0>(gpb + 32 * H_,  Bs + (SLOT) * 4096 + (tid + 256) * 8);\
        gpb += 64;                                                       \
    } while (0)
#define ISSUE_AB(SLOT) do { ISSUE_A(SLOT); ISSUE_B(SLOT); } while (0)

    // frag offsets (elems): row*64 + ((cc*4+fq) ^ (row&7))*8; row&7 == fr&7.
    const int xr0 = (fq ^ (fr & 7)) * 8;
    const int xr1 = ((4 + fq) ^ (fr & 7)) * 8;
    int aoff[4][2], boff[2][2];
#pragma unroll
    for (int i = 0; i < 4; ++i) {
        aoff[i][0] = (wm + i * 16 + fr) * 64 + xr0;
        aoff[i][1] = (wm + i * 16 + fr) * 64 + xr1;
    }
#pragma unroll
    for (int j = 0; j < 2; ++j) {
        boff[j][0] = (wn + j * 16 + fr) * 64 + xr0;
        boff[j][1] = (wn + j * 16 + fr) * 64 + xr1;
    }

#define COMPUTE(SLOT)                                                       \
    {                                                                       \
        _Pragma("unroll")                                                   \
        for (int cc = 0; cc < 2; ++cc) {                                    \
            bf16x8 af[4], bfv[2];                                           \
            _Pragma("unroll")                                               \
            for (int j = 0; j < 2; ++j)                                     \
                bfv[j] = *(const bf16x8*)(Bs + (SLOT) * 4096 + boff[j][cc]);\
            _Pragma("unroll")                                               \
            for (int i = 0; i < 4; ++i)                                     \
                af[i] = *(const bf16x8*)(As + (SLOT) * 8192 + aoff[i][cc]); \
            _Pragma("unroll")                                               \
            for (int i = 0; i < 4; ++i)                                     \
                _Pragma("unroll")                                           \
                for (int j = 0; j < 2; ++j)                                 \
                    acc[i][j] = __builtin_amdgcn_mfma_f32_16x16x32_bf16(    \
                        af[i], bfv[j], acc[i][j], 0, 0, 0);                 \
        }                                                                   \
    }

    // epilogue constants (step-invariant)
    float wv[2], bv[2];
    int xbase[4];
#pragma unroll
    for (int j = 0; j < 2; ++j) {
        const int col = bn * 64 + wn + j * 16 + fr;
        wv[j] = Whx[col];
        bv[j] = bh[col];
    }
#pragma unroll
    for (int i = 0; i < 4; ++i)
        xbase[i] = (bm * 128 + wm + i * 16 + fq * 4) * T_;

    for (int t = 1; t < T_; ++t) {
        const bf16_t* __restrict__ Abuf = g_hb[(t - 1) & 1];
        bf16_t* __restrict__ hn = g_hb[t & 1];
        const bf16_t* gpa = Abuf + aofsg;
        const bf16_t* gpb = gb0;

        // B stages 0..2: immutable data, issue before the dependency wait.
        ISSUE_B(0); ISSUE_B(1); ISSUE_B(2);

        // wait until all 32 same-XCD writers of h-rows bm finished step t-1
        if (tid == 0) {
            while (__hip_atomic_load(&g_cnt[(t - 1) * 8 + bm], __ATOMIC_RELAXED,
                                     __HIP_MEMORY_SCOPE_AGENT) != 32)
                __builtin_amdgcn_s_sleep(2);
        }
        __syncthreads();          // no agent fence: sc0 A-loads read fresh L2

        ISSUE_A(0); ISSUE_A(1); ISSUE_A(2);

        f32x4 acc[4][2];
#pragma unroll
        for (int i = 0; i < 4; ++i)
#pragma unroll
            for (int j = 0; j < 2; ++j) acc[i][j] = (f32x4)(0.f);

        // Queue order: B0 B1 B2 | A0 A1 A2 | S3 S4 ... (A=4, B=2 loads).
        // it0 needs B0+A0 -> vmcnt 8; it1 +A1 -> 10; it2 -> 12; steady 12.
        wait_vm_barrier<8>();  ISSUE_AB(3); COMPUTE(0);
        wait_vm_barrier<10>(); ISSUE_AB(0); COMPUTE(1);
        wait_vm_barrier<12>(); ISSUE_AB(1); COMPUTE(2);
        for (int g = 0; g < 6; ++g) {
#pragma unroll
            for (int u = 0; u < 4; ++u) {     // iters 3..26
                wait_vm_barrier<12>();
                ISSUE_AB((u + 2) & 3);
                COMPUTE((u + 3) & 3);
            }
        }
        wait_vm_barrier<12>(); ISSUE_AB(2); COMPUTE(3);   // it27 (stage 30)
        wait_vm_barrier<12>(); ISSUE_AB(3); COMPUTE(0);   // it28 (stage 31)
        wait_vm_barrier<12>(); COMPUTE(1);                // drain
        wait_vm_barrier<6>();  COMPUTE(2);
        wait_vm_barrier<0>();  COMPUTE(3);

        // epilogue: + x_t*W_hx + b_h, tanh, bf16 store
#pragma unroll
        for (int i = 0; i < 4; ++i) {
            const int row0 = bm * 128 + wm + i * 16 + fq * 4;
            float xv[4];
#pragma unroll
            for (int r = 0; r < 4; ++r) xv[r] = x[xbase[i] + r * T_ + t];
#pragma unroll
            for (int j = 0; j < 2; ++j) {
                const int col = bn * 64 + wn + j * 16 + fr;
#pragma unroll
                for (int r = 0; r < 4; ++r)
                    hn[(size_t)(row0 + r) * H_ + col] =
                        (bf16_t)tanhf(acc[i][j][r] + xv[r] * wv[j] + bv[j]);
            }
        }

        // publish: drain this wave's stores to L2, join waves, bump counter.
        asm volatile("s_waitcnt vmcnt(0)" ::: "memory");
        __syncthreads();
        if (tid == 0)
            __hip_atomic_fetch_add(&g_cnt[t * 8 + bm], 1, __ATOMIC_RELAXED,
                                   __HIP_MEMORY_SCOPE_AGENT);
    }
#undef COMPUTE
#undef ISSUE_AB
#undef ISSUE_B
#undef ISSUE_A
}

// p = h_T @ W_ph + b_p : one wave per batch row, fp32 accumulate.
__global__ __launch_bounds__(64) void rnn_proj(const float* __restrict__ Wph,
                                               const float* __restrict__ bp,
                                               float* __restrict__ out, int sb) {
    const int b = blockIdx.x;
    const int l = threadIdx.x;
    const bf16_t* h = g_hb[sb] + (size_t)b * H_;
    float acc[C_];
#pragma unroll
    for (int c = 0; c < C_; ++c) acc[c] = 0.f;
    for (int k = l; k < H_; k += 64) {
        const float hv = (float)h[k];
#pragma unroll
        for (int c = 0; c < C_; ++c)
            acc[c] = fmaf(hv, Wph[k * C_ + c], acc[c]);
    }
#pragma unroll
    for (int off = 32; off > 0; off >>= 1)
#pragma unroll
        for (int c = 0; c < C_; ++c) acc[c] += __shfl_down(acc[c], off);
    if (l == 0) {
#pragma unroll
        for (int c = 0; c < C_; ++c) out[b * C_ + c] = acc[c] + bp[c];
    }
}

extern "C" void kernel_launch(void* const* d_in, const int* in_sizes, int n_in,
                              void* d_out, int out_size, void* d_ws, size_t ws_size,
                              hipStream_t stream) {
    const float* x   = (const float*)d_in[0];   // [1024,128]
    const float* Whx = (const float*)d_in[1];   // [1,2048]
    const float* Whh = (const float*)d_in[2];   // [2048,2048]
    const float* bh  = (const float*)d_in[3];   // [2048]
    const float* Wph = (const float*)d_in[4];   // [2048,10]
    const float* bp  = (const float*)d_in[5];   // [1,10]
    float* out = (float*)d_out;                 // [1024,10]

    static bool attr_set = false;
    if (!attr_set) {
        hipFuncSetAttribute((const void*)rnn_persist,
                            hipFuncAttributeMaxDynamicSharedMemorySize, 98304);
        attr_set = true;
    }

    prep_whhT<<<dim3(64, 64), 256, 0, stream>>>(Whh);
    rnn_init<<<(B_ * H_ / 4) / 256, 256, 0, stream>>>(x, Whx, bh);
    rnn_persist<<<256, 256, 98304, stream>>>(x, Whx, bh);
    rnn_proj<<<B_, 64, 0, stream>>>(Wph, bp, out, (T_ - 1) & 1);
}

// Round 11
// 2471.106 us; speedup vs baseline: 3.1454x; 1.0437x over previous
//
#include <hip/hip_runtime.h>
#include <math.h>

#define B_ 1024
#define T_ 128
#define H_ 2048
#define C_ 10

typedef __bf16 bf16_t;
typedef __bf16 bf16x8 __attribute__((ext_vector_type(8)));
typedef __bf16 bf16x4 __attribute__((ext_vector_type(4)));
typedef float f32x4 __attribute__((ext_vector_type(4)));

// Static device storage: bf16 h ping-pong (8 MB), bf16 W_hh^T (8 MB),
// per-(t,bm) readiness counters (XCD-local handoff).
__device__ __align__(16) bf16_t g_hb[2][(size_t)B_ * H_];
__device__ __align__(16) bf16_t g_whhT[(size_t)H_ * H_];
__device__ int g_cnt[T_ * 8];   // [t][bm]; t=0 seeded to 32 by rnn_init

// AUX: cache policy. 0 = default; 1 = sc0 (force L1 miss -> read XCD L2).
template <int AUX>
__device__ __forceinline__ void gload16(const bf16_t* g, bf16_t* l) {
    __builtin_amdgcn_global_load_lds(
        (const __attribute__((address_space(1))) void*)g,
        (__attribute__((address_space(3))) void*)l, 16, 0, AUX);
}

// Counted-vmcnt barrier: retire oldest pipeline stage without draining.
template <int VM>
__device__ __forceinline__ void wait_vm_barrier() {
    asm volatile("s_waitcnt vmcnt(%0)\n\ts_barrier" :: "n"(VM) : "memory");
}

// One-time: W_hhT[n][k] = bf16(W_hh[k][n]) — B operand must be K-contiguous.
__global__ __launch_bounds__(256) void prep_whhT(const float* __restrict__ Whh) {
    __shared__ float tile[32][33];
    const int i  = threadIdx.x >> 3;
    const int j4 = (threadIdx.x & 7) * 4;
    const int r0 = blockIdx.y * 32;
    const int c0 = blockIdx.x * 32;
    f32x4 v = *(const f32x4*)(Whh + (size_t)(r0 + i) * H_ + c0 + j4);
    tile[i][j4 + 0] = v[0]; tile[i][j4 + 1] = v[1];
    tile[i][j4 + 2] = v[2]; tile[i][j4 + 3] = v[3];
    __syncthreads();
    bf16x4 o;
#pragma unroll
    for (int r = 0; r < 4; ++r) o[r] = (bf16_t)tile[j4 + r][i];
    *(bf16x4*)&g_whhT[(size_t)(c0 + i) * H_ + r0 + j4] = o;
}

// t = 0: h = tanh(x[:,0]*W_hx + b_h); also (re)initialize the counters.
__global__ __launch_bounds__(256) void rnn_init(const float* __restrict__ x,
                                                const float* __restrict__ Whx,
                                                const float* __restrict__ bh) {
    if (blockIdx.x == 0) {
        for (int i = threadIdx.x; i < T_ * 8; i += 256)
            g_cnt[i] = (i < 8) ? 32 : 0;   // g_cnt[0][*] = 32 (h0 ready)
    }
    const int gid = blockIdx.x * 256 + threadIdx.x;
    const int row = gid >> 9;
    const int col = (gid & 511) << 2;
    const float xv = x[(size_t)row * T_];
    f32x4 w = *(const f32x4*)&Whx[col];
    f32x4 b = *(const f32x4*)&bh[col];
    bf16x4 o;
#pragma unroll
    for (int j = 0; j < 4; ++j) o[j] = (bf16_t)tanhf(fmaf(xv, w[j], b[j]));
    *(bf16x4*)&g_hb[0][(size_t)row * H_ + col] = o;
}

// Persistent RNN, XCD-local sync (r10) + two anti-stall levers:
//  (1) zig-zag K order per step (odd t reads K descending) so the LRU tail
//      of W_hh^T from step t is L2-hot at the start of step t+1;
//  (2) 6-stage LDS ring (147 KB), 5 stages in flight, steady vmcnt(24) --
//      ~5 iterations of latency look-ahead for residual L3 misses.
// Map bm = li&7 = XCD: writers/readers of h-rows bm share one L2. Writers
// drain stores (vmcnt(0)), publish via relaxed agent atomic; readers poll
// and stage A with sc0 loads (bypass stale L1). B is immutable (aux=0).
__global__ __launch_bounds__(256, 1) void rnn_persist(const float* __restrict__ x,
                                                      const float* __restrict__ Whx,
                                                      const float* __restrict__ bh) {
    extern __shared__ __align__(16) bf16_t smem[];
    bf16_t* As = smem;                 // 6 stages x 8192 elems (16 KB)
    bf16_t* Bs = smem + 6 * 8192;      // 6 stages x 4096 elems (8 KB)

    const int tid  = threadIdx.x;
    const int lane = tid & 63;
    const int wave = tid >> 6;
    const int li  = blockIdx.x;
    const int bm  = li & 7;                          // == XCD (blk%8 map)
    const int bn  = li >> 3;                         // 0..31

    const int wm = (wave & 1) * 64, wn = (wave >> 1) * 32;
    const int fr = lane & 15, fq = lane >> 4;

    // Staging: linear slot s holds row s>>3, lds-chunk s&7;
    // global chunk = (s&7) ^ (row&7)  (8-row spread -> 2-way frag reads).
    const int rA = tid >> 3;                         // 0..31
    const int cg = (tid & 7) ^ (rA & 7);
    const size_t aofsg = (size_t)(bm * 128 + rA) * H_ + cg * 8;
    const bf16_t* const gb0 = g_whhT + (size_t)(bn * 64 + rA) * H_ + cg * 8;

#define ISSUE_A(SLOT)                                                    \
    do {                                                                 \
        gload16<1>(gpa,            As + (SLOT) * 8192 + tid * 8);        \
        gload16<1>(gpa + 32 * H_,  As + (SLOT) * 8192 + (tid + 256) * 8);\
        gload16<1>(gpa + 64 * H_,  As + (SLOT) * 8192 + (tid + 512) * 8);\
        gload16<1>(gpa + 96 * H_,  As + (SLOT) * 8192 + (tid + 768) * 8);\
        gpa += kstep;                                                    \
    } while (0)
#define ISSUE_B(SLOT)                                                    \
    do {                                                                 \
        gload16<0>(gpb,            Bs + (SLOT) * 4096 + tid * 8);        \
        gload16<0>(gpb + 32 * H_,  Bs + (SLOT) * 4096 + (tid + 256) * 8);\
        gpb += kstep;                                                    \
    } while (0)
#define ISSUE_AB(SLOT) do { ISSUE_A(SLOT); ISSUE_B(SLOT); } while (0)

    // frag offsets (elems): row*64 + ((cc*4+fq) ^ (row&7))*8; row&7 == fr&7.
    const int xr0 = (fq ^ (fr & 7)) * 8;
    const int xr1 = ((4 + fq) ^ (fr & 7)) * 8;
    int aoff[4][2], boff[2][2];
#pragma unroll
    for (int i = 0; i < 4; ++i) {
        aoff[i][0] = (wm + i * 16 + fr) * 64 + xr0;
        aoff[i][1] = (wm + i * 16 + fr) * 64 + xr1;
    }
#pragma unroll
    for (int j = 0; j < 2; ++j) {
        boff[j][0] = (wn + j * 16 + fr) * 64 + xr0;
        boff[j][1] = (wn + j * 16 + fr) * 64 + xr1;
    }

#define COMPUTE(SLOT)                                                       \
    {                                                                       \
        _Pragma("unroll")                                                   \
        for (int cc = 0; cc < 2; ++cc) {                                    \
            bf16x8 af[4], bfv[2];                                           \
            _Pragma("unroll")                                               \
            for (int j = 0; j < 2; ++j)                                     \
                bfv[j] = *(const bf16x8*)(Bs + (SLOT) * 4096 + boff[j][cc]);\
            _Pragma("unroll")                                               \
            for (int i = 0; i < 4; ++i)                                     \
                af[i] = *(const bf16x8*)(As + (SLOT) * 8192 + aoff[i][cc]); \
            _Pragma("unroll")                                               \
            for (int i = 0; i < 4; ++i)                                     \
                _Pragma("unroll")                                           \
                for (int j = 0; j < 2; ++j)                                 \
                    acc[i][j] = __builtin_amdgcn_mfma_f32_16x16x32_bf16(    \
                        af[i], bfv[j], acc[i][j], 0, 0, 0);                 \
        }                                                                   \
    }

    // epilogue constants (step-invariant)
    float wv[2], bv[2];
    int xbase[4];
#pragma unroll
    for (int j = 0; j < 2; ++j) {
        const int col = bn * 64 + wn + j * 16 + fr;
        wv[j] = Whx[col];
        bv[j] = bh[col];
    }
#pragma unroll
    for (int i = 0; i < 4; ++i)
        xbase[i] = (bm * 128 + wm + i * 16 + fq * 4) * T_;

    for (int t = 1; t < T_; ++t) {
        const bf16_t* __restrict__ Abuf = g_hb[(t - 1) & 1];
        bf16_t* __restrict__ hn = g_hb[t & 1];
        // zig-zag: odd steps walk K from the top -- L2 still holds that tail
        const int koff  = (t & 1) ? (H_ - 64) : 0;
        const int kstep = (t & 1) ? -64 : 64;
        const bf16_t* gpa = Abuf + aofsg + koff;
        const bf16_t* gpb = gb0 + koff;

        // B stages 0..4: immutable data, issue before the dependency wait.
        ISSUE_B(0); ISSUE_B(1); ISSUE_B(2); ISSUE_B(3); ISSUE_B(4);

        // wait until all 32 same-XCD writers of h-rows bm finished step t-1
        if (tid == 0) {
            while (__hip_atomic_load(&g_cnt[(t - 1) * 8 + bm], __ATOMIC_RELAXED,
                                     __HIP_MEMORY_SCOPE_AGENT) != 32)
                __builtin_amdgcn_s_sleep(2);
        }
        __syncthreads();          // no agent fence: sc0 A-loads read fresh L2

        ISSUE_A(0); ISSUE_A(1); ISSUE_A(2); ISSUE_A(3); ISSUE_A(4);

        f32x4 acc[4][2];
#pragma unroll
        for (int i = 0; i < 4; ++i)
#pragma unroll
            for (int j = 0; j < 2; ++j) acc[i][j] = (f32x4)(0.f);

        // Queue: B0..B4 (10 loads) | A0..A4 (20) | stage 5.. (6/stage).
        // A_i retires at graded vmcnt; steady state = vmcnt(24) (1 stage).
        wait_vm_barrier<16>(); ISSUE_AB(5); COMPUTE(0);   // it0
        wait_vm_barrier<18>(); ISSUE_AB(0); COMPUTE(1);   // it1
        wait_vm_barrier<20>(); ISSUE_AB(1); COMPUTE(2);   // it2
        wait_vm_barrier<22>(); ISSUE_AB(2); COMPUTE(3);   // it3
        wait_vm_barrier<24>(); ISSUE_AB(3); COMPUTE(4);   // it4
        for (int g = 0; g < 3; ++g) {                     // its 5..22
#pragma unroll
            for (int u = 0; u < 6; ++u) {
                wait_vm_barrier<24>();
                ISSUE_AB((u + 4) % 6);
                COMPUTE((u + 5) % 6);
            }
        }
        wait_vm_barrier<24>(); ISSUE_AB(4); COMPUTE(5);   // it23 (stage 28)
        wait_vm_barrier<24>(); ISSUE_AB(5); COMPUTE(0);   // it24 (stage 29)
        wait_vm_barrier<24>(); ISSUE_AB(0); COMPUTE(1);   // it25 (stage 30)
        wait_vm_barrier<24>(); ISSUE_AB(1); COMPUTE(2);   // it26 (stage 31)
        wait_vm_barrier<24>(); COMPUTE(3);                // drain its 27..31
        wait_vm_barrier<18>(); COMPUTE(4);
        wait_vm_barrier<12>(); COMPUTE(5);
        wait_vm_barrier<6>();  COMPUTE(0);
        wait_vm_barrier<0>();  COMPUTE(1);

        // epilogue: + x_t*W_hx + b_h, tanh, bf16 store
#pragma unroll
        for (int i = 0; i < 4; ++i) {
            const int row0 = bm * 128 + wm + i * 16 + fq * 4;
            float xv[4];
#pragma unroll
            for (int r = 0; r < 4; ++r) xv[r] = x[xbase[i] + r * T_ + t];
#pragma unroll
            for (int j = 0; j < 2; ++j) {
                const int col = bn * 64 + wn + j * 16 + fr;
#pragma unroll
                for (int r = 0; r < 4; ++r)
                    hn[(size_t)(row0 + r) * H_ + col] =
                        (bf16_t)tanhf(acc[i][j][r] + xv[r] * wv[j] + bv[j]);
            }
        }

        // publish: drain this wave's stores to L2, join waves, bump counter.
        asm volatile("s_waitcnt vmcnt(0)" ::: "memory");
        __syncthreads();
        if (tid == 0)
            __hip_atomic_fetch_add(&g_cnt[t * 8 + bm], 1, __ATOMIC_RELAXED,
                                   __HIP_MEMORY_SCOPE_AGENT);
    }
#undef COMPUTE
#undef ISSUE_AB
#undef ISSUE_B
#undef ISSUE_A
}

// p = h_T @ W_ph + b_p : one wave per batch row, fp32 accumulate.
__global__ __launch_bounds__(64) void rnn_proj(const float* __restrict__ Wph,
                                               const float* __restrict__ bp,
                                               float* __restrict__ out, int sb) {
    const int b = blockIdx.x;
    const int l = threadIdx.x;
    const bf16_t* h = g_hb[sb] + (size_t)b * H_;
    float acc[C_];
#pragma unroll
    for (int c = 0; c < C_; ++c) acc[c] = 0.f;
    for (int k = l; k < H_; k += 64) {
        const float hv = (float)h[k];
#pragma unroll
        for (int c = 0; c < C_; ++c)
            acc[c] = fmaf(hv, Wph[k * C_ + c], acc[c]);
    }
#pragma unroll
    for (int off = 32; off > 0; off >>= 1)
#pragma unroll
        for (int c = 0; c < C_; ++c) acc[c] += __shfl_down(acc[c], off);
    if (l == 0) {
#pragma unroll
        for (int c = 0; c < C_; ++c) out[b * C_ + c] = acc[c] + bp[c];
    }
}

extern "C" void kernel_launch(void* const* d_in, const int* in_sizes, int n_in,
                              void* d_out, int out_size, void* d_ws, size_t ws_size,
                              hipStream_t stream) {
    const float* x   = (const float*)d_in[0];   // [1024,128]
    const float* Whx = (const float*)d_in[1];   // [1,2048]
    const float* Whh = (const float*)d_in[2];   // [2048,2048]
    const float* bh  = (const float*)d_in[3];   // [2048]
    const float* Wph = (const float*)d_in[4];   // [2048,10]
    const float* bp  = (const float*)d_in[5];   // [1,10]
    float* out = (float*)d_out;                 // [1024,10]

    static bool attr_set = false;
    if (!attr_set) {
        hipFuncSetAttribute((const void*)rnn_persist,
                            hipFuncAttributeMaxDynamicSharedMemorySize, 147456);
        attr_set = true;
    }

    prep_whhT<<<dim3(64, 64), 256, 0, stream>>>(Whh);
    rnn_init<<<(B_ * H_ / 4) / 256, 256, 0, stream>>>(x, Whx, bh);
    rnn_persist<<<256, 256, 147456, stream>>>(x, Whx, bh);
    rnn_proj<<<B_, 64, 0, stream>>>(Wph, bp, out, (T_ - 1) & 1);
}